// Round 1
// baseline (546.414 us; speedup 1.0000x reference)
//
#include <hip/hip_runtime.h>
#include <hip/hip_bf16.h>
#include <stdint.h>

// Problem constants (fixed by setup_inputs)
#define NS     512          // N samples
#define KSEG   16           // segments
#define SEGD   8192         // elements per segment (L*C/K)
#define KFULL  131072       // L*C per sample
#define TEMP_INV (1.0f/0.7f)

typedef __attribute__((ext_vector_type(8))) short  bf16x8;
typedef __attribute__((ext_vector_type(4))) float  f32x4;

__device__ __forceinline__ void glds16(const void* g, void* l) {
    __builtin_amdgcn_global_load_lds(
        (const __attribute__((address_space(1))) void*)g,
        (__attribute__((address_space(3))) void*)l,
        16, 0, 0);
}

// ---------------- kernel 1: fp32 -> bf16 conversion (memory-bound) ----------
__device__ __forceinline__ unsigned bf16rne(float x) {
    unsigned u = __float_as_uint(x);
    return (u + 0x7fffu + ((u >> 16) & 1u)) >> 16;   // RNE, inputs are finite
}

__global__ __launch_bounds__(256) void cvt_bf16(const float* __restrict__ in,
                                                uint4* __restrict__ out, int n8) {
    const int stride = gridDim.x * blockDim.x;
    for (int i = blockIdx.x * blockDim.x + threadIdx.x; i < n8; i += stride) {
        const float4* p = (const float4*)in + (size_t)i * 2;
        float4 v0 = p[0], v1 = p[1];
        uint4 o;
        o.x = bf16rne(v0.x) | (bf16rne(v0.y) << 16);
        o.y = bf16rne(v0.z) | (bf16rne(v0.w) << 16);
        o.z = bf16rne(v1.x) | (bf16rne(v1.y) << 16);
        o.w = bf16rne(v1.z) | (bf16rne(v1.w) << 16);
        out[i] = o;
    }
}

// ---------------- kernel 2: per-segment F F^T (bf16 MFMA, split-K=2) --------
// grid = (4, 4, 32): x=a-tile, y=b-tile, z = seg*2 + khalf
// 128x128 tile, BK=64, 4 waves (2x2), each wave 64x64 via 4x4 16x16x32 MFMAs.
__global__ __launch_bounds__(256, 2) void gemm_bt(const __hip_bfloat16* __restrict__ F,
                                                  float* __restrict__ part) {
    __shared__ __hip_bfloat16 As[128 * 64];
    __shared__ __hip_bfloat16 Bs[128 * 64];

    const int bx = blockIdx.x, by = blockIdx.y, bz = blockIdx.z;
    const int seg = bz >> 1, half = bz & 1;
    const int tid = threadIdx.x;
    const int lane = tid & 63;
    const int wid  = tid >> 6;
    const int wm = wid >> 1, wn = wid & 1;

    const size_t kbase0 = (size_t)seg * SEGD + (size_t)half * (SEGD / 2);
    const int arow0 = bx * 128, brow0 = by * 128;

    // staging: each wave covers 32 rows (4 instrs x 8 rows); lane l -> row +l>>3, 16B chunk l&7
    const int s_r = (lane >> 3);
    const int s_c = (lane & 7) * 8;     // elements

    f32x4 acc[4][4];
    #pragma unroll
    for (int m = 0; m < 4; ++m)
        #pragma unroll
        for (int n = 0; n < 4; ++n)
            acc[m][n] = (f32x4){0.f, 0.f, 0.f, 0.f};

    const int a_r  = wm * 64 + (lane & 15);   // + m*16
    const int b_r  = wn * 64 + (lane & 15);   // + n*16
    const int k_off = (lane >> 4) * 8;        // + kk*32

    for (int kt = 0; kt < (SEGD / 2) / 64; ++kt) {
        __syncthreads();   // previous iter's LDS reads complete before overwrite
        const size_t kb = kbase0 + (size_t)kt * 64;
        #pragma unroll
        for (int i = 0; i < 4; ++i) {
            const int r0 = wid * 32 + i * 8;
            glds16(F + (size_t)(arow0 + r0 + s_r) * KFULL + kb + s_c, &As[r0 * 64]);
            glds16(F + (size_t)(brow0 + r0 + s_r) * KFULL + kb + s_c, &Bs[r0 * 64]);
        }
        __syncthreads();   // compiler drains vmcnt(0) before s_barrier

        bf16x8 af[4][2], bf[4][2];
        #pragma unroll
        for (int m = 0; m < 4; ++m)
            #pragma unroll
            for (int kk = 0; kk < 2; ++kk)
                af[m][kk] = *(const bf16x8*)&As[(a_r + m * 16) * 64 + kk * 32 + k_off];
        #pragma unroll
        for (int n = 0; n < 4; ++n)
            #pragma unroll
            for (int kk = 0; kk < 2; ++kk)
                bf[n][kk] = *(const bf16x8*)&Bs[(b_r + n * 16) * 64 + kk * 32 + k_off];
        #pragma unroll
        for (int m = 0; m < 4; ++m)
            #pragma unroll
            for (int n = 0; n < 4; ++n)
                #pragma unroll
                for (int kk = 0; kk < 2; ++kk)
                    acc[m][n] = __builtin_amdgcn_mfma_f32_16x16x32_bf16(
                        af[m][kk], bf[n][kk], acc[m][n], 0, 0, 0);
    }

    // write fp32 partials: plane (half*16+seg), row-major [NS][NS]
    float* out = part + ((size_t)(half * KSEG + seg) << 18);
    const int row0 = arow0 + wm * 64 + (lane >> 4) * 4;   // + m*16 + j
    const int col0 = brow0 + wn * 64 + (lane & 15);       // + n*16
    #pragma unroll
    for (int m = 0; m < 4; ++m)
        #pragma unroll
        for (int n = 0; n < 4; ++n)
            #pragma unroll
            for (int j = 0; j < 4; ++j)
                out[(size_t)(row0 + m * 16 + j) * NS + col0 + n * 16] = acc[m][n][j];
}

// ---------------- kernel 3: epilogue — top4/sum loss, masked mean -----------
__global__ __launch_bounds__(256) void loss_k(const float* __restrict__ part,
                                              const int* __restrict__ labels,
                                              float* __restrict__ out) {
    const int idx = blockIdx.x * 256 + threadIdx.x;   // a*512 + b
    const int a = idx >> 9, b = idx & (NS - 1);
    const float* p = part + idx;

    float s[16];
    float mx = -3.4e38f;
    #pragma unroll
    for (int k = 0; k < 16; ++k) {
        float v = (p[(size_t)k << 18] + p[(size_t)(k + 16) << 18]) * TEMP_INV;
        s[k] = v;
        mx = fmaxf(mx, v);
    }
    float sum = 0.f;
    #pragma unroll
    for (int k = 0; k < 16; ++k) { s[k] = expf(s[k] - mx); sum += s[k]; }

    float t0 = -1.f, t1 = -1.f, t2 = -1.f, t3 = -1.f;   // exp(x) > 0 always
    #pragma unroll
    for (int k = 0; k < 16; ++k) {
        float v = s[k];
        if      (v > t0) { t3 = t2; t2 = t1; t1 = t0; t0 = v; }
        else if (v > t1) { t3 = t2; t2 = t1; t1 = v; }
        else if (v > t2) { t3 = t2; t2 = v; }
        else if (v > t3) { t3 = v; }
    }

    float loss = 0.f;
    if (a != b && labels[a] == labels[b])
        loss = -logf((t0 + t1 + t2 + t3) / sum);

    #pragma unroll
    for (int off = 32; off > 0; off >>= 1) loss += __shfl_down(loss, off);
    if ((threadIdx.x & 63) == 0)
        atomicAdd(out, loss * (1.0f / ((float)NS * (float)NS)));
}

// ---------------- launch ----------------------------------------------------
extern "C" void kernel_launch(void* const* d_in, const int* in_sizes, int n_in,
                              void* d_out, int out_size, void* d_ws, size_t ws_size,
                              hipStream_t stream) {
    const float* features = (const float*)d_in[0];
    const int*   labels   = (const int*)d_in[1];
    // d_in[2] (preds) unused by the loss
    float* out = (float*)d_out;
    char*  ws  = (char*)d_ws;

    // ws layout: [0, 134217728)  bf16 F   (512*131072*2)
    //            [134217728, +33554432)  fp32 partials [2*16][512][512]
    __hip_bfloat16* Fbf  = (__hip_bfloat16*)ws;
    float*          part = (float*)(ws + (size_t)NS * KFULL * 2);

    hipMemsetAsync(d_out, 0, sizeof(float), stream);

    cvt_bf16<<<2048, 256, 0, stream>>>(features, (uint4*)Fbf, (NS * KFULL) / 8);

    dim3 g(4, 4, KSEG * 2);
    gemm_bt<<<g, 256, 0, stream>>>(Fbf, part);

    loss_k<<<(NS * NS) / 256, 256, 0, stream>>>(part, labels, out);
}